// Round 5
// baseline (2443.077 us; speedup 1.0000x reference)
//
#include <hip/hip_runtime.h>
#include <hip/hip_bf16.h>
#include <hip/hip_fp16.h>
#include <stdint.h>

constexpr int kT = 512;

// d_ws byte offsets
constexpr uint32_t WHP_OFF  = 0u;        // [64][512][8] fp16 : Wh[h][kb*8+e]
constexpr uint32_t WRSP_OFF = 524288u;   // [32][512][8] fp16 : Wr+Wr' summed
constexpr uint32_t WSP_OFF  = 786432u;   // [64][128][8] fp16 : Ws[o][kb*8+e]
constexpr uint32_t WEP_OFF  = 917504u;   // [32][512][8] bf16 : We[h][kb*8+e]
constexpr uint32_t BIAS_OFF = 1179648u;  // [512] f32
constexpr uint32_t X_OFF    = 1181696u;  // [2][64][4][128] u32 tag|fp16 exchange

// d_out element offsets (fp32)
constexpr uint32_t OUT_HL = 16777216u;
constexpr uint32_t OUT_SR = 16809984u;

static __device__ __forceinline__ float bitsf(uint32_t u) {
  union { uint32_t u; float f; } c; c.u = u; return c.f;
}

typedef _Float16 h2_t __attribute__((ext_vector_type(2)));

static __device__ __forceinline__ float dot2acc(uint32_t w, uint32_t h, float acc) {
#if __has_builtin(__builtin_amdgcn_fdot2)
  return __builtin_amdgcn_fdot2(__builtin_bit_cast(h2_t, w),
                                __builtin_bit_cast(h2_t, h), acc, false);
#else
  h2_t wv = __builtin_bit_cast(h2_t, w), hv = __builtin_bit_cast(h2_t, h);
  return acc + (float)wv.x * (float)hv.x + (float)wv.y * (float)hv.y;
#endif
}

static __device__ __forceinline__ float dot8h(uint4 w, uint4 h, float acc) {
  acc = dot2acc(w.x, h.x, acc);
  acc = dot2acc(w.y, h.y, acc);
  acc = dot2acc(w.z, h.z, acc);
  acc = dot2acc(w.w, h.w, acc);
  return acc;
}

// opaque keep-alive: blocks load rematerialization of register-resident weights
#define KEEP4(v) asm volatile("" : "+v"((v).x), "+v"((v).y), "+v"((v).z), "+v"((v).w))

// ---------------- kernel 0: pack weights + fold biases ----------------
__global__ __launch_bounds__(256) void pack_kernel(
    const float* __restrict__ Wh, const float* __restrict__ Wr,
    const float* __restrict__ Ws, const float* __restrict__ We,
    const float* __restrict__ be, const float* __restrict__ bh,
    const float* __restrict__ br, char* __restrict__ ws)
{
  uint32_t g = blockIdx.x * 256u + threadIdx.x;
  __half* whp  = (__half*)(ws + WHP_OFF);
  __half* wrsp = (__half*)(ws + WRSP_OFF);
  __half* wsp  = (__half*)(ws + WSP_OFF);
  __hip_bfloat16* wep = (__hip_bfloat16*)(ws + WEP_OFF);
  float* bias = (float*)(ws + BIAS_OFF);

  if (g < 262144u) {
    uint32_t e = g & 7u, h = (g >> 3) & 511u, kb = g >> 12;
    whp[g] = __float2half(Wh[h * 512u + kb * 8u + e]);
  }
  if (g < 131072u) {
    uint32_t e = g & 7u, h = (g >> 3) & 511u, jb = g >> 12;
    wrsp[g] = __float2half(Wr[h * 256u + jb * 8u + e] +
                           Wr[(512u + h) * 256u + jb * 8u + e]);
  }
  if (g < 65536u) {
    uint32_t e = g & 7u, o = (g >> 3) & 127u, kb = g >> 10;
    wsp[g] = __float2half(Ws[o * 512u + kb * 8u + e]);
  }
  if (g < 131072u) {
    uint32_t e = g & 7u, h = (g >> 3) & 511u, kb = g >> 12;
    wep[g] = __float2bfloat16(We[h * 256u + kb * 8u + e]);
  }
  if (g < 512u) bias[g] = be[g] + bh[g] + br[g] + br[512u + g];
}

// ---------------- kernel 1: E = emb @ We.T + biases -> d_out output region --------
__global__ __launch_bounds__(256) void embed_kernel(
    const float* __restrict__ embs, const char* __restrict__ ws,
    float* __restrict__ out)
{
  __shared__ __align__(16) float embL[16 * 256];
  const uint32_t tid = threadIdx.x;
  const uint32_t r0 = blockIdx.x * 16u;
  #pragma unroll
  for (int i = 0; i < 16; i++) embL[tid + i * 256] = embs[r0 * 256u + tid + i * 256u];
  __syncthreads();

  const uint4* wep = (const uint4*)(ws + WEP_OFF);
  const float* bias = (const float*)(ws + BIAS_OFF);

  for (int hb = 0; hb < 2; hb++) {
    uint32_t h = hb * 256u + tid;
    float acc[16];
    #pragma unroll
    for (int r = 0; r < 16; r++) acc[r] = 0.f;
    for (int kb = 0; kb < 32; kb++) {
      uint4 v = wep[kb * 512u + h];
      float w0 = bitsf(v.x << 16), w1 = bitsf(v.x & 0xffff0000u);
      float w2 = bitsf(v.y << 16), w3 = bitsf(v.y & 0xffff0000u);
      float w4 = bitsf(v.z << 16), w5 = bitsf(v.z & 0xffff0000u);
      float w6 = bitsf(v.w << 16), w7 = bitsf(v.w & 0xffff0000u);
      #pragma unroll
      for (int r = 0; r < 16; r++) {
        const float4* e4 = (const float4*)&embL[r * 256 + kb * 8];
        float4 a = e4[0], c = e4[1];
        acc[r] += w0 * a.x + w1 * a.y + w2 * a.z + w3 * a.w
                + w4 * c.x + w5 * c.y + w6 * c.z + w7 * c.w;
      }
    }
    float bi = bias[h];
    #pragma unroll
    for (int r = 0; r < 16; r++) out[(r0 + r) * 512u + h] = acc[r] + bi;
  }
}

// ---- kernel 2: recurrence, 512 thr/WG, 4-way row split x 2 batches interleaved ----
__global__ __launch_bounds__(512, 2) void rnn_kernel(
    const int* __restrict__ lens, const float* __restrict__ Wa,
    const float* __restrict__ ba, const float* __restrict__ bs,
    const float* __restrict__ memb, char* __restrict__ ws,
    float* __restrict__ out)
{
  __shared__ __align__(16) float stk[2][2][4096];   // [batch][buf] 64 KB
  __shared__ __align__(16) __half waH[3072];
  __shared__ __align__(16) __half hH[2][2][512];    // perm ph2 layout
  __shared__ __align__(16) __half tH[2][2][256];    // perm ph3 layout
  __shared__ __align__(16) float pvL[2][128];
  __shared__ __align__(16) float membL[128];
  __shared__ float bsL[128];
  __shared__ float lgts[2][8];
  __shared__ float baL[8];

  const uint32_t tid = threadIdx.x;
  const uint32_t wg = blockIdx.x;
  const uint32_t q = wg >> 5;          // row quarter 0..3
  const uint32_t p = wg & 31u;         // batch pair; blocks {p,32+p,64+p,96+p} ≡ p mod 8 -> same XCD
  const uint32_t b0 = 2u * p, b1 = 2u * p + 1u;
  const int len0 = lens[b0], len1 = lens[b1];
  const uint32_t r = tid >> 2, s = tid & 3u;   // row-in-quarter, K-slice
  const uint32_t h = q * 128u + r;

  const uint4* whp  = (const uint4*)(ws + WHP_OFF);
  const uint4* wrsp = (const uint4*)(ws + WRSP_OFF);
  const uint4* wsp  = (const uint4*)(ws + WSP_OFF);
  uint32_t* X32 = (uint32_t*)(ws + X_OFF);

  // ---- weights into VGPRs: Wh quarter 64 + Wrs quarter 32 + Ws FULL 64 = 160 regs
  uint4 wh[16], wrs[8], wsr[16];
  #pragma unroll
  for (int i = 0; i < 16; i++) wh[i]  = whp[(s * 16u + (uint32_t)i) * 512u + h];
  #pragma unroll
  for (int i = 0; i < 8; i++)  wrs[i] = wrsp[(s * 8u + (uint32_t)i) * 512u + h];
  #pragma unroll
  for (int i = 0; i < 16; i++) wsr[i] = wsp[(s * 16u + (uint32_t)i) * 128u + r];
  #pragma unroll
  for (int i = 0; i < 16; i++) KEEP4(wh[i]);
  #pragma unroll
  for (int i = 0; i < 8; i++)  KEEP4(wrs[i]);
  #pragma unroll
  for (int i = 0; i < 16; i++) KEEP4(wsr[i]);

  // ---- init
  for (uint32_t i = tid; i < 3072u; i += 512u) waH[i] = __float2half(Wa[i]);
  if (tid < 128u) {
    membL[tid] = memb[tid]; bsL[tid] = bs[tid];
    uint32_t u = tid >> 6, sl = tid & 63u;
    ((uint4*)hH[u][0])[sl] = uint4{0u, 0u, 0u, 0u};
  }
  {  // tops init = mem_bias, perm ph3
    uint32_t u = tid >> 8, f = tid & 255u;
    uint32_t jb = f >> 3, e = f & 7u, n = f >> 7, d = f & 63u;
    uint32_t pt = ((jb & 7u) << 2) | (jb >> 3);
    ((__half*)tH[u][0])[pt * 8u + e] = __float2half(memb[n * 64u + d]);
  }
  if (tid < 8u) baL[tid] = (tid < 6u) ? ba[tid] : 0.f;
  __syncthreads();
  #pragma unroll
  for (int u = 0; u < 2; u++) {
    #pragma unroll
    for (int hv = 0; hv < 2; hv++) {
      uint32_t c = tid * 8u + (uint32_t)hv * 4u;
      uint32_t n = c >> 11, d = c & 63u;
      *(float4*)&stk[u][0][c] = *(const float4*)&membL[n * 64u + d];
    }
  }
  float eCur0 = (s == 0) ? out[b0 * 512u + h] : 0.f;
  float eCur1 = (s == 0) ? out[b1 * 512u + h] : 0.f;
  __syncthreads();

  for (int t = 0; t < kT; t++) {
    const int cur = t & 1, nxt = cur ^ 1;
    float eN0 = 0.f, eN1 = 0.f;
    if (s == 0 && t < kT - 1) {
      eN0 = out[((uint32_t)(t + 1) * 64u + b0) * 512u + h];
      eN1 = out[((uint32_t)(t + 1) * 64u + b1) * 512u + h];
    }

    // ---- A phase: both batches (mhid, push_vals, logits)
    #pragma unroll
    for (int u = 0; u < 2; u++) {
      const uint32_t bu = u ? b1 : b0;
      const float eC = u ? eCur1 : eCur0;
      const int lenU = u ? len1 : len0;
      const uint4* hc = (const uint4*)hH[u][cur];
      const uint4* tc = (const uint4*)tH[u][cur];

      float acc = 0.f;
      #pragma unroll
      for (int i = 0; i < 16; i++) acc = dot8h(wh[i], hc[(uint32_t)i * 4u + s], acc);
      #pragma unroll
      for (int i = 0; i < 8; i++)  acc = dot8h(wrs[i], tc[(uint32_t)i * 4u + s], acc);
      acc += __shfl_xor(acc, 1, 64);
      acc += __shfl_xor(acc, 2, 64);
      if (s == 0) {
        float v = tanhf(acc + eC);
        out[((uint32_t)t * 64u + bu) * 512u + h] = v;
        if (t == lenU - 1) out[OUT_HL + bu * 512u + h] = v;
        __half vh = __float2half(v);
        uint32_t pay = ((uint32_t)(t + 1) << 16) | (uint32_t)__half_as_ushort(vh);
        __hip_atomic_store(&X32[(((uint32_t)cur * 64u + bu) * 4u + q) * 128u + r], pay,
                           __ATOMIC_RELAXED, __HIP_MEMORY_SCOPE_AGENT);
        uint32_t kb = h >> 3, e = h & 7u;
        uint32_t ph = ((kb & 15u) << 2) | (kb >> 4);
        ((__half*)hH[u][nxt])[ph * 8u + e] = vh;   // own quarter, next buffer
      }
      // push_vals fully replicated (Ws in VGPRs)
      float wa2 = 0.f;
      #pragma unroll
      for (int i = 0; i < 16; i++) wa2 = dot8h(wsr[i], hc[(uint32_t)i * 4u + s], wa2);
      wa2 += __shfl_xor(wa2, 1, 64);
      wa2 += __shfl_xor(wa2, 2, 64);
      if (s == 0) pvL[u][r] = tanhf(wa2 + bsL[r]);
      // action logits (replicated)
      if (tid < 384u) {
        uint32_t o = tid >> 6, kb = tid & 63u;
        uint32_t ph = ((kb & 15u) << 2) | (kb >> 4);
        float la = dot8h(((const uint4*)waH)[o * 64u + kb], hc[ph], 0.f);
        #pragma unroll
        for (int off = 1; off <= 32; off <<= 1) la += __shfl_xor(la, off, 64);
        if (kb == 0) lgts[u][o] = la + baL[o];
      }
    }
    eCur0 = eN0; eCur1 = eN1;
    __syncthreads();

    // ---- C phase: stack blend both batches (replicated, bit-identical across WGs)
    #pragma unroll
    for (int u = 0; u < 2; u++) {
      const uint32_t bu = u ? b1 : b0;
      const int lenU = u ? len1 : len0;
      const bool lastT = (t == lenU - 1);
      uint32_t c0 = tid * 8u;
      uint32_t n = c0 >> 11, sd = (c0 >> 6) & 31u;
      float l0 = lgts[u][n * 3u], l1 = lgts[u][n * 3u + 1u], l2 = lgts[u][n * 3u + 2u];
      float m = fmaxf(l0, fmaxf(l1, l2));
      float e0 = __expf(l0 - m), e1 = __expf(l1 - m), e2 = __expf(l2 - m);
      float inv = 1.f / (e0 + e1 + e2);
      float p0 = e0 * inv, p1 = e1 * inv, p2 = e2 * inv;
      #pragma unroll
      for (int hv = 0; hv < 2; hv++) {
        uint32_t c = c0 + (uint32_t)hv * 4u;
        uint32_t d = c & 63u;
        float4 scur = *(const float4*)&stk[u][cur][c];
        float4 sp = (sd == 0) ? *(const float4*)&pvL[u][n * 64u + d]
                              : *(const float4*)&stk[u][cur][c - 64u];
        float4 so = (sd == 31u) ? *(const float4*)&membL[n * 64u + d]
                                : *(const float4*)&stk[u][cur][c + 64u];
        float4 nv;
        nv.x = p0 * sp.x + p1 * so.x + p2 * scur.x;
        nv.y = p0 * sp.y + p1 * so.y + p2 * scur.y;
        nv.z = p0 * sp.z + p1 * so.z + p2 * scur.z;
        nv.w = p0 * sp.w + p1 * so.w + p2 * scur.w;
        *(float4*)&stk[u][nxt][c] = nv;
        if (sd < 2u) {  // new tops -> perm ph3, next buffer
          uint32_t f = n * 128u + sd * 64u + d;
          uint32_t jb = f >> 3, e = f & 7u;
          uint32_t pt = ((jb & 7u) << 2) | (jb >> 3);
          uint32_t lo = ((uint32_t)__half_as_ushort(__float2half(nv.y)) << 16) |
                        __half_as_ushort(__float2half(nv.x));
          uint32_t hi = ((uint32_t)__half_as_ushort(__float2half(nv.w)) << 16) |
                        __half_as_ushort(__float2half(nv.z));
          *(uint2*)((__half*)tH[u][nxt] + pt * 8u + e) = uint2{lo, hi};
        }
        if (lastT && q == 0u) *(float4*)&out[OUT_SR + bu * 4096u + c] = nv;
      }
    }

    // ---- gather foreign hid quarters (latency hidden under A(x2)+C(x2))
    if (t < kT - 1 && tid < 384u) {
      #pragma unroll
      for (int u = 0; u < 2; u++) {
        const uint32_t bu = u ? b1 : b0;
        uint32_t j = tid >> 7;
        uint32_t jj = j + (j >= q ? 1u : 0u);
        uint32_t k = tid & 127u;
        uint32_t* src = &X32[(((uint32_t)cur * 64u + bu) * 4u + jj) * 128u + k];
        const uint32_t want = (uint32_t)(t + 1) << 16;
        uint32_t x = __hip_atomic_load(src, __ATOMIC_RELAXED, __HIP_MEMORY_SCOPE_AGENT);
        uint32_t g = 0;
        while ((x & 0xffff0000u) != want) {
          x = __hip_atomic_load(src, __ATOMIC_RELAXED, __HIP_MEMORY_SCOPE_AGENT);
          if (++g > (1u << 24)) break;   // bounded: no hang even if model wrong
        }
        uint32_t idx = jj * 128u + k, kb = idx >> 3, e = idx & 7u;
        uint32_t ph = ((kb & 15u) << 2) | (kb >> 4);
        ((__half*)hH[u][nxt])[ph * 8u + e] =
            __ushort_as_half((unsigned short)(x & 0xffffu));
      }
    }
    __syncthreads();
  }
}

extern "C" void kernel_launch(void* const* d_in, const int* in_sizes, int n_in,
                              void* d_out, int out_size, void* d_ws, size_t ws_size,
                              hipStream_t stream) {
  const float* embs = (const float*)d_in[0];
  const int*   lens = (const int*)d_in[1];
  const float* We   = (const float*)d_in[2];
  const float* be   = (const float*)d_in[3];
  const float* Wh   = (const float*)d_in[4];
  const float* bh   = (const float*)d_in[5];
  const float* Wa   = (const float*)d_in[6];
  const float* ba   = (const float*)d_in[7];
  const float* Ws   = (const float*)d_in[8];
  const float* bs   = (const float*)d_in[9];
  const float* Wr   = (const float*)d_in[10];
  const float* br   = (const float*)d_in[11];
  const float* memb = (const float*)d_in[12];
  float* out = (float*)d_out;
  char* ws = (char*)d_ws;

  pack_kernel<<<1024, 256, 0, stream>>>(Wh, Wr, Ws, We, be, bh, br, ws);
  embed_kernel<<<2048, 256, 0, stream>>>(embs, ws, out);
  rnn_kernel<<<128, 512, 0, stream>>>(lens, Wa, ba, bs, memb, ws, out);
}

// Round 6
// 1301.786 us; speedup vs baseline: 1.8767x; 1.8767x over previous
//
#include <hip/hip_runtime.h>
#include <hip/hip_bf16.h>
#include <hip/hip_fp16.h>
#include <stdint.h>

constexpr int kT = 512;

// d_ws byte offsets
constexpr uint32_t WHP_OFF  = 0u;        // [64][512][8] fp16 : Wh[h][kb*8+e]
constexpr uint32_t WRSP_OFF = 524288u;   // [32][512][8] fp16 : Wr+Wr' summed
constexpr uint32_t WSP_OFF  = 786432u;   // [64][128][8] fp16 : Ws[o][kb*8+e]
constexpr uint32_t WEP_OFF  = 917504u;   // [32][512][8] bf16 : We[h][kb*8+e]
constexpr uint32_t BIAS_OFF = 1179648u;  // [512] f32
constexpr uint32_t X_OFF    = 1181696u;  // [2][64][4][128] u32 tag|fp16 exchange

// d_out element offsets (fp32)
constexpr uint32_t OUT_HL = 16777216u;
constexpr uint32_t OUT_SR = 16809984u;

static __device__ __forceinline__ float bitsf(uint32_t u) {
  union { uint32_t u; float f; } c; c.u = u; return c.f;
}

typedef _Float16 h2_t __attribute__((ext_vector_type(2)));

static __device__ __forceinline__ float dot2acc(uint32_t w, uint32_t h, float acc) {
#if __has_builtin(__builtin_amdgcn_fdot2)
  return __builtin_amdgcn_fdot2(__builtin_bit_cast(h2_t, w),
                                __builtin_bit_cast(h2_t, h), acc, false);
#else
  h2_t wv = __builtin_bit_cast(h2_t, w), hv = __builtin_bit_cast(h2_t, h);
  return acc + (float)wv.x * (float)hv.x + (float)wv.y * (float)hv.y;
#endif
}

static __device__ __forceinline__ float dot8h(uint4 w, uint4 h, float acc) {
  acc = dot2acc(w.x, h.x, acc);
  acc = dot2acc(w.y, h.y, acc);
  acc = dot2acc(w.z, h.z, acc);
  acc = dot2acc(w.w, h.w, acc);
  return acc;
}

// opaque keep-alive: blocks load rematerialization of register-resident weights
#define KEEP4(v) asm volatile("" : "+v"((v).x), "+v"((v).y), "+v"((v).z), "+v"((v).w))

// ---------------- kernel 0: pack weights + fold biases ----------------
__global__ __launch_bounds__(256) void pack_kernel(
    const float* __restrict__ Wh, const float* __restrict__ Wr,
    const float* __restrict__ Ws, const float* __restrict__ We,
    const float* __restrict__ be, const float* __restrict__ bh,
    const float* __restrict__ br, char* __restrict__ ws)
{
  uint32_t g = blockIdx.x * 256u + threadIdx.x;
  __half* whp  = (__half*)(ws + WHP_OFF);
  __half* wrsp = (__half*)(ws + WRSP_OFF);
  __half* wsp  = (__half*)(ws + WSP_OFF);
  __hip_bfloat16* wep = (__hip_bfloat16*)(ws + WEP_OFF);
  float* bias = (float*)(ws + BIAS_OFF);

  if (g < 262144u) {
    uint32_t e = g & 7u, h = (g >> 3) & 511u, kb = g >> 12;
    whp[g] = __float2half(Wh[h * 512u + kb * 8u + e]);
  }
  if (g < 131072u) {
    uint32_t e = g & 7u, h = (g >> 3) & 511u, jb = g >> 12;
    wrsp[g] = __float2half(Wr[h * 256u + jb * 8u + e] +
                           Wr[(512u + h) * 256u + jb * 8u + e]);
  }
  if (g < 65536u) {
    uint32_t e = g & 7u, o = (g >> 3) & 127u, kb = g >> 10;
    wsp[g] = __float2half(Ws[o * 512u + kb * 8u + e]);
  }
  if (g < 131072u) {
    uint32_t e = g & 7u, h = (g >> 3) & 511u, kb = g >> 12;
    wep[g] = __float2bfloat16(We[h * 256u + kb * 8u + e]);
  }
  if (g < 512u) bias[g] = be[g] + bh[g] + br[g] + br[512u + g];
}

// ---------------- kernel 1: E = emb @ We.T + biases -> d_out output region --------
__global__ __launch_bounds__(256) void embed_kernel(
    const float* __restrict__ embs, const char* __restrict__ ws,
    float* __restrict__ out)
{
  __shared__ __align__(16) float embL[16 * 256];
  const uint32_t tid = threadIdx.x;
  const uint32_t r0 = blockIdx.x * 16u;
  #pragma unroll
  for (int i = 0; i < 16; i++) embL[tid + i * 256] = embs[r0 * 256u + tid + i * 256u];
  __syncthreads();

  const uint4* wep = (const uint4*)(ws + WEP_OFF);
  const float* bias = (const float*)(ws + BIAS_OFF);

  for (int hb = 0; hb < 2; hb++) {
    uint32_t h = hb * 256u + tid;
    float acc[16];
    #pragma unroll
    for (int r = 0; r < 16; r++) acc[r] = 0.f;
    for (int kb = 0; kb < 32; kb++) {
      uint4 v = wep[kb * 512u + h];
      float w0 = bitsf(v.x << 16), w1 = bitsf(v.x & 0xffff0000u);
      float w2 = bitsf(v.y << 16), w3 = bitsf(v.y & 0xffff0000u);
      float w4 = bitsf(v.z << 16), w5 = bitsf(v.z & 0xffff0000u);
      float w6 = bitsf(v.w << 16), w7 = bitsf(v.w & 0xffff0000u);
      #pragma unroll
      for (int r = 0; r < 16; r++) {
        const float4* e4 = (const float4*)&embL[r * 256 + kb * 8];
        float4 a = e4[0], c = e4[1];
        acc[r] += w0 * a.x + w1 * a.y + w2 * a.z + w3 * a.w
                + w4 * c.x + w5 * c.y + w6 * c.z + w7 * c.w;
      }
    }
    float bi = bias[h];
    #pragma unroll
    for (int r = 0; r < 16; r++) out[(r0 + r) * 512u + h] = acc[r] + bi;
  }
}

// ---- kernel 2: recurrence, 4 WGs/batch; Wh+Ws in VGPRs, Wrs in LDS (swizzled) ----
__global__ __launch_bounds__(1024) void rnn_kernel(
    const int* __restrict__ lens, const float* __restrict__ Wa,
    const float* __restrict__ ba, const float* __restrict__ bs,
    const float* __restrict__ memb, char* __restrict__ ws,
    float* __restrict__ out)
{
  __shared__ __align__(16) uint4 wrsL[32 * 128];  // 64 KB: Wrs quarter, XOR-swizzled
  __shared__ __align__(16) float stk[2][4096];    // 32 KB stack dbuf (replicated)
  __shared__ __align__(16) __half waH[3072];      //  6 KB Wa fp16
  __shared__ __align__(16) __half hH[2][512];     //  2 KB hid dbuf, perm layout
  __shared__ __align__(16) __half tH[2][256];     //  1 KB tops dbuf, perm layout
  __shared__ __align__(16) float pvL[128];
  __shared__ __align__(16) float membL[128];
  __shared__ float bsL[128];
  __shared__ float lgts[8];
  __shared__ float baL[8];

  const uint32_t tid = threadIdx.x;
  const uint32_t wg = blockIdx.x;
  const uint32_t q = wg >> 6;      // quarter 0..3 (wg = q*64+b keeps group on one XCD)
  const uint32_t b = wg & 63u;
  const int len = lens[b];
  const uint32_t r = tid >> 3, s = tid & 7u;   // row-in-quarter, K-slice
  const uint32_t h = q * 128u + r;

  const uint4* whp  = (const uint4*)(ws + WHP_OFF);
  const uint4* wrsp = (const uint4*)(ws + WRSP_OFF);
  const uint4* wsp  = (const uint4*)(ws + WSP_OFF);
  uint32_t* X32 = (uint32_t*)(ws + X_OFF);

  // ---- register-resident: Wh quarter 32 + Ws FULL 32 = 64 VGPRs (fits under 128 cap)
  uint4 wh[8], wsr[8];
  #pragma unroll
  for (int i = 0; i < 8; i++) wh[i]  = whp[(s * 8u + (uint32_t)i) * 512u + h];
  #pragma unroll
  for (int j = 0; j < 8; j++) wsr[j] = wsp[(s * 8u + (uint32_t)j) * 128u + r];
  #pragma unroll
  for (int i = 0; i < 8; i++) KEEP4(wh[i]);
  #pragma unroll
  for (int i = 0; i < 8; i++) KEEP4(wsr[i]);

  // ---- Wrs quarter -> LDS, swizzled: wrsL[jb*128 + (rr ^ (jb>>2))]
  #pragma unroll
  for (int i = 0; i < 4; i++) {
    uint32_t f = (uint32_t)i * 1024u + tid;        // f = jb*128 + rr, coalesced
    uint32_t jb = f >> 7, rr = f & 127u;
    wrsL[jb * 128u + (rr ^ (jb >> 2))] = wrsp[jb * 512u + q * 128u + rr];
  }

  for (uint32_t i = tid; i < 3072u; i += 1024u) waH[i] = __float2half(Wa[i]);
  if (tid < 128u) { membL[tid] = memb[tid]; bsL[tid] = bs[tid]; }
  if (tid < 64u)  ((uint4*)hH[0])[tid] = uint4{0u, 0u, 0u, 0u};
  if (tid < 256u) {  // tops init = mem_bias, perm layout
    uint32_t jb = tid >> 3, e = tid & 7u, n = tid >> 7, d = tid & 63u;
    uint32_t pt = ((jb & 3u) << 3) | (jb >> 2);
    ((__half*)tH[0])[pt * 8u + e] = __float2half(memb[n * 64u + d]);
  }
  if (tid < 8u) baL[tid] = (tid < 6u) ? ba[tid] : 0.f;
  __syncthreads();
  {
    uint32_t c = tid * 4u, n = c >> 11, d = c & 63u;
    *(float4*)&stk[0][c] = *(const float4*)&membL[n * 64u + d];
  }
  float eCur = (s == 0) ? out[b * 512u + h] : 0.f;
  __syncthreads();

  for (int t = 0; t < kT; t++) {
    const int cur = t & 1, nxt = cur ^ 1;
    const bool lastT = (t == len - 1);
    const uint4* hc = (const uint4*)hH[cur];
    const uint4* tc = (const uint4*)tH[cur];

    float eNext = (s == 0 && t < kT - 1)
                ? out[((uint32_t)(t + 1) * 64u + b) * 512u + h] : 0.f;

    // ---- A1: mhid row h (Wh in VGPRs, Wrs from swizzled LDS; hid/tops broadcast)
    float acc = 0.f;
    #pragma unroll
    for (int i = 0; i < 8; i++) acc = dot8h(wh[i], hc[(uint32_t)i * 8u + s], acc);
    #pragma unroll
    for (int i = 0; i < 4; i++) {
      uint32_t jb = s * 4u + (uint32_t)i;
      acc = dot8h(wrsL[jb * 128u + (r ^ s)], tc[(uint32_t)i * 8u + s], acc);
    }
    acc += __shfl_xor(acc, 1, 64);
    acc += __shfl_xor(acc, 2, 64);
    acc += __shfl_xor(acc, 4, 64);
    if (s == 0) {
      float v = tanhf(acc + eCur);
      out[((uint32_t)t * 64u + b) * 512u + h] = v;
      if (lastT) out[OUT_HL + b * 512u + h] = v;
      __half vh = __float2half(v);
      uint32_t pay = ((uint32_t)(t + 1) << 16) | (uint32_t)__half_as_ushort(vh);
      __hip_atomic_store(&X32[(((uint32_t)cur * 64u + b) * 4u + q) * 128u + r], pay,
                         __ATOMIC_RELAXED, __HIP_MEMORY_SCOPE_AGENT);
      uint32_t kb = h >> 3, e = h & 7u;
      uint32_t ph = ((kb & 7u) << 3) | (kb >> 3);
      ((__half*)hH[nxt])[ph * 8u + e] = vh;   // own quarter, next buffer
    }
    eCur = eNext;

    // ---- A2: FULL push_vals (replicated; Ws in VGPRs -> no exchange needed)
    float wa2 = 0.f;
    #pragma unroll
    for (int j = 0; j < 8; j++) wa2 = dot8h(wsr[j], hc[((uint32_t)j << 3) | s], wa2);
    wa2 += __shfl_xor(wa2, 1, 64);
    wa2 += __shfl_xor(wa2, 2, 64);
    wa2 += __shfl_xor(wa2, 4, 64);
    if (s == 0) pvL[r] = tanhf(wa2 + bsL[r]);

    // ---- A3: action logits (replicated)
    if (tid < 384u) {
      uint32_t o = tid >> 6, kb = tid & 63u;
      uint32_t ph = ((kb & 7u) << 3) | (kb >> 3);
      float la = dot8h(((const uint4*)waH)[o * 64u + kb], hc[ph], 0.f);
      #pragma unroll
      for (int off = 1; off <= 32; off <<= 1) la += __shfl_xor(la, off, 64);
      if (kb == 0) lgts[o] = la + baL[o];
    }
    __syncthreads();

    // ---- C: stack blend (replicated, bit-identical across the 4 WGs)
    {
      uint32_t c = tid * 4u;
      uint32_t n = c >> 11, sd = (tid >> 4) & 31u, d = c & 63u;
      float l0 = lgts[n * 3u], l1 = lgts[n * 3u + 1u], l2 = lgts[n * 3u + 2u];
      float m = fmaxf(l0, fmaxf(l1, l2));
      float e0 = __expf(l0 - m), e1 = __expf(l1 - m), e2 = __expf(l2 - m);
      float inv = 1.f / (e0 + e1 + e2);
      float p0 = e0 * inv, p1 = e1 * inv, p2 = e2 * inv;
      float4 scur = *(const float4*)&stk[cur][c];
      float4 sp = (sd == 0) ? *(const float4*)&pvL[n * 64u + d]
                            : *(const float4*)&stk[cur][c - 64u];
      float4 so = (sd == 31u) ? *(const float4*)&membL[n * 64u + d]
                              : *(const float4*)&stk[cur][c + 64u];
      float4 nv;
      nv.x = p0 * sp.x + p1 * so.x + p2 * scur.x;
      nv.y = p0 * sp.y + p1 * so.y + p2 * scur.y;
      nv.z = p0 * sp.z + p1 * so.z + p2 * scur.z;
      nv.w = p0 * sp.w + p1 * so.w + p2 * scur.w;
      *(float4*)&stk[nxt][c] = nv;
      if (sd < 2u) {  // new tops -> perm-layout fp16 (next buffer)
        uint32_t f = n * 128u + sd * 64u + d;
        uint32_t jb = f >> 3, e = f & 7u;
        uint32_t pt = ((jb & 3u) << 3) | (jb >> 2);
        uint32_t lo = ((uint32_t)__half_as_ushort(__float2half(nv.y)) << 16) |
                      __half_as_ushort(__float2half(nv.x));
        uint32_t hi = ((uint32_t)__half_as_ushort(__float2half(nv.w)) << 16) |
                      __half_as_ushort(__float2half(nv.z));
        *(uint2*)((__half*)tH[nxt] + pt * 8u + e) = uint2{lo, hi};
      }
      if (lastT && q == 0u) *(float4*)&out[OUT_SR + b * 4096u + c] = nv;
    }

    // ---- gather the 3 foreign hid quarters (store latency hidden under A2/A3/C)
    if (t < kT - 1 && tid < 384u) {
      uint32_t j = tid >> 7;
      uint32_t jj = j + (j >= q ? 1u : 0u);
      uint32_t k = tid & 127u;
      uint32_t* src = &X32[(((uint32_t)cur * 64u + b) * 4u + jj) * 128u + k];
      const uint32_t want = (uint32_t)(t + 1) << 16;
      uint32_t x = __hip_atomic_load(src, __ATOMIC_RELAXED, __HIP_MEMORY_SCOPE_AGENT);
      uint32_t g = 0;
      while ((x & 0xffff0000u) != want) {
        x = __hip_atomic_load(src, __ATOMIC_RELAXED, __HIP_MEMORY_SCOPE_AGENT);
        if (++g > (1u << 24)) break;   // bounded: no hang even if model wrong
      }
      uint32_t idx = jj * 128u + k, kb = idx >> 3, e = idx & 7u;
      uint32_t ph = ((kb & 7u) << 3) | (kb >> 3);
      ((__half*)hH[nxt])[ph * 8u + e] = __ushort_as_half((unsigned short)(x & 0xffffu));
    }
    __syncthreads();
  }
}

extern "C" void kernel_launch(void* const* d_in, const int* in_sizes, int n_in,
                              void* d_out, int out_size, void* d_ws, size_t ws_size,
                              hipStream_t stream) {
  const float* embs = (const float*)d_in[0];
  const int*   lens = (const int*)d_in[1];
  const float* We   = (const float*)d_in[2];
  const float* be   = (const float*)d_in[3];
  const float* Wh   = (const float*)d_in[4];
  const float* bh   = (const float*)d_in[5];
  const float* Wa   = (const float*)d_in[6];
  const float* ba   = (const float*)d_in[7];
  const float* Ws   = (const float*)d_in[8];
  const float* bs   = (const float*)d_in[9];
  const float* Wr   = (const float*)d_in[10];
  const float* br   = (const float*)d_in[11];
  const float* memb = (const float*)d_in[12];
  float* out = (float*)d_out;
  char* ws = (char*)d_ws;

  pack_kernel<<<1024, 256, 0, stream>>>(Wh, Wr, Ws, We, be, bh, br, ws);
  embed_kernel<<<2048, 256, 0, stream>>>(embs, ws, out);
  rnn_kernel<<<256, 1024, 0, stream>>>(lens, Wa, ba, bs, memb, ws, out);
}

// Round 7
// 1251.770 us; speedup vs baseline: 1.9517x; 1.0400x over previous
//
#include <hip/hip_runtime.h>
#include <hip/hip_bf16.h>
#include <hip/hip_fp16.h>
#include <stdint.h>

constexpr int kT = 512;

// d_ws byte offsets
constexpr uint32_t WHP_OFF  = 0u;        // [64][512][8] fp16 : Wh[h][kb*8+e]
constexpr uint32_t WRSP_OFF = 524288u;   // [32][512][8] fp16 : Wr+Wr' summed
constexpr uint32_t WSP_OFF  = 786432u;   // [64][128][8] fp16 : Ws[o][kb*8+e]
constexpr uint32_t WEP_OFF  = 917504u;   // [32][512][8] bf16 : We[h][kb*8+e]
constexpr uint32_t BIAS_OFF = 1179648u;  // [512] f32
constexpr uint32_t X_OFF    = 1181696u;  // [2][64][4][128] u32 tag|fp16 exchange

// d_out element offsets (fp32)
constexpr uint32_t OUT_HL = 16777216u;
constexpr uint32_t OUT_SR = 16809984u;

static __device__ __forceinline__ float bitsf(uint32_t u) {
  union { uint32_t u; float f; } c; c.u = u; return c.f;
}

typedef _Float16 h2_t __attribute__((ext_vector_type(2)));

static __device__ __forceinline__ float dot2acc(uint32_t w, uint32_t h, float acc) {
#if __has_builtin(__builtin_amdgcn_fdot2)
  return __builtin_amdgcn_fdot2(__builtin_bit_cast(h2_t, w),
                                __builtin_bit_cast(h2_t, h), acc, false);
#else
  h2_t wv = __builtin_bit_cast(h2_t, w), hv = __builtin_bit_cast(h2_t, h);
  return acc + (float)wv.x * (float)hv.x + (float)wv.y * (float)hv.y;
#endif
}

static __device__ __forceinline__ float dot8h(uint4 w, uint4 h, float acc) {
  acc = dot2acc(w.x, h.x, acc);
  acc = dot2acc(w.y, h.y, acc);
  acc = dot2acc(w.z, h.z, acc);
  acc = dot2acc(w.w, h.w, acc);
  return acc;
}

// opaque keep-alive: blocks load rematerialization of register-resident weights
#define KEEP4(v) asm volatile("" : "+v"((v).x), "+v"((v).y), "+v"((v).z), "+v"((v).w))

// ---------------- kernel 0: pack weights + fold biases ----------------
__global__ __launch_bounds__(256) void pack_kernel(
    const float* __restrict__ Wh, const float* __restrict__ Wr,
    const float* __restrict__ Ws, const float* __restrict__ We,
    const float* __restrict__ be, const float* __restrict__ bh,
    const float* __restrict__ br, char* __restrict__ ws)
{
  uint32_t g = blockIdx.x * 256u + threadIdx.x;
  __half* whp  = (__half*)(ws + WHP_OFF);
  __half* wrsp = (__half*)(ws + WRSP_OFF);
  __half* wsp  = (__half*)(ws + WSP_OFF);
  __hip_bfloat16* wep = (__hip_bfloat16*)(ws + WEP_OFF);
  float* bias = (float*)(ws + BIAS_OFF);

  if (g < 262144u) {
    uint32_t e = g & 7u, h = (g >> 3) & 511u, kb = g >> 12;
    whp[g] = __float2half(Wh[h * 512u + kb * 8u + e]);
  }
  if (g < 131072u) {
    uint32_t e = g & 7u, h = (g >> 3) & 511u, jb = g >> 12;
    wrsp[g] = __float2half(Wr[h * 256u + jb * 8u + e] +
                           Wr[(512u + h) * 256u + jb * 8u + e]);
  }
  if (g < 65536u) {
    uint32_t e = g & 7u, o = (g >> 3) & 127u, kb = g >> 10;
    wsp[g] = __float2half(Ws[o * 512u + kb * 8u + e]);
  }
  if (g < 131072u) {
    uint32_t e = g & 7u, h = (g >> 3) & 511u, kb = g >> 12;
    wep[g] = __float2bfloat16(We[h * 256u + kb * 8u + e]);
  }
  if (g < 512u) bias[g] = be[g] + bh[g] + br[g] + br[512u + g];
}

// ---------------- kernel 1: E = emb @ We.T + biases -> d_out output region --------
__global__ __launch_bounds__(256) void embed_kernel(
    const float* __restrict__ embs, const char* __restrict__ ws,
    float* __restrict__ out)
{
  __shared__ __align__(16) float embL[16 * 256];
  const uint32_t tid = threadIdx.x;
  const uint32_t r0 = blockIdx.x * 16u;
  #pragma unroll
  for (int i = 0; i < 16; i++) embL[tid + i * 256] = embs[r0 * 256u + tid + i * 256u];
  __syncthreads();

  const uint4* wep = (const uint4*)(ws + WEP_OFF);
  const float* bias = (const float*)(ws + BIAS_OFF);

  for (int hb = 0; hb < 2; hb++) {
    uint32_t h = hb * 256u + tid;
    float acc[16];
    #pragma unroll
    for (int r = 0; r < 16; r++) acc[r] = 0.f;
    for (int kb = 0; kb < 32; kb++) {
      uint4 v = wep[kb * 512u + h];
      float w0 = bitsf(v.x << 16), w1 = bitsf(v.x & 0xffff0000u);
      float w2 = bitsf(v.y << 16), w3 = bitsf(v.y & 0xffff0000u);
      float w4 = bitsf(v.z << 16), w5 = bitsf(v.z & 0xffff0000u);
      float w6 = bitsf(v.w << 16), w7 = bitsf(v.w & 0xffff0000u);
      #pragma unroll
      for (int r = 0; r < 16; r++) {
        const float4* e4 = (const float4*)&embL[r * 256 + kb * 8];
        float4 a = e4[0], c = e4[1];
        acc[r] += w0 * a.x + w1 * a.y + w2 * a.z + w3 * a.w
                + w4 * c.x + w5 * c.y + w6 * c.z + w7 * c.w;
      }
    }
    float bi = bias[h];
    #pragma unroll
    for (int r = 0; r < 16; r++) out[(r0 + r) * 512u + h] = acc[r] + bi;
  }
}

// ---- kernel 2: recurrence, 4 WGs/batch; Wh+Ws in VGPRs (128 cap), Wrs in LDS ----
__global__ __launch_bounds__(1024, 4) void rnn_kernel(
    const int* __restrict__ lens, const float* __restrict__ Wa,
    const float* __restrict__ ba, const float* __restrict__ bs,
    const float* __restrict__ memb, char* __restrict__ ws,
    float* __restrict__ out)
{
  __shared__ __align__(16) uint4 wrsL[4096];      // 64 KB: Wrs quarter, [i][r][s] linear
  __shared__ __align__(16) float stk[2][4096];    // 32 KB stack dbuf (replicated)
  __shared__ __align__(16) __half waH[3072];      //  6 KB Wa fp16
  __shared__ __align__(16) __half hH[2][512];     //  2 KB hid dbuf, perm layout
  __shared__ __align__(16) __half tH[2][256];     //  1 KB tops dbuf, perm layout
  __shared__ __align__(16) float pvL[128];
  __shared__ __align__(16) float membL[128];
  __shared__ float bsL[128];
  __shared__ float lgts[8];
  __shared__ float baL[8];

  const uint32_t tid = threadIdx.x;
  const uint32_t wg = blockIdx.x;
  const uint32_t q = wg >> 6;      // quarter 0..3 (wg = q*64+b keeps group on one XCD)
  const uint32_t b = wg & 63u;
  const int len = lens[b];
  const uint32_t r = tid >> 3, s = tid & 7u;   // row-in-quarter, K-slice
  const uint32_t h = q * 128u + r;

  const uint4* whp  = (const uint4*)(ws + WHP_OFF);
  const uint4* wrsp = (const uint4*)(ws + WRSP_OFF);
  const uint4* wsp  = (const uint4*)(ws + WSP_OFF);
  uint32_t* X32 = (uint32_t*)(ws + X_OFF);

  // ---- register-resident: Wh quarter 32 + Ws FULL 32 = 64 VGPRs (under the 128 cap)
  uint4 wh[8], wsr[8];
  #pragma unroll
  for (int i = 0; i < 8; i++) wh[i]  = whp[(s * 8u + (uint32_t)i) * 512u + h];
  #pragma unroll
  for (int j = 0; j < 8; j++) wsr[j] = wsp[(s * 8u + (uint32_t)j) * 128u + r];
  #pragma unroll
  for (int i = 0; i < 8; i++) KEEP4(wh[i]);
  #pragma unroll
  for (int i = 0; i < 8; i++) KEEP4(wsr[i]);

  // ---- Wrs quarter -> LDS, layout [i][r][s]: read index = i*1024 + lane-linear
  #pragma unroll
  for (int i = 0; i < 4; i++) {
    wrsL[(uint32_t)i * 1024u + r * 8u + s] =
        wrsp[(s * 4u + (uint32_t)i) * 512u + q * 128u + r];
  }

  for (uint32_t i = tid; i < 3072u; i += 1024u) waH[i] = __float2half(Wa[i]);
  if (tid < 128u) { membL[tid] = memb[tid]; bsL[tid] = bs[tid]; }
  if (tid < 64u)  ((uint4*)hH[0])[tid] = uint4{0u, 0u, 0u, 0u};
  if (tid < 256u) {  // tops init = mem_bias, perm layout
    uint32_t jb = tid >> 3, e = tid & 7u, n = tid >> 7, d = tid & 63u;
    uint32_t pt = ((jb & 3u) << 3) | (jb >> 2);
    ((__half*)tH[0])[pt * 8u + e] = __float2half(memb[n * 64u + d]);
  }
  if (tid < 8u) baL[tid] = (tid < 6u) ? ba[tid] : 0.f;
  __syncthreads();
  {
    uint32_t c = tid * 4u, n = c >> 11, d = c & 63u;
    *(float4*)&stk[0][c] = *(const float4*)&membL[n * 64u + d];
  }
  float eCur = (s == 0) ? out[b * 512u + h] : 0.f;
  __syncthreads();

  for (int t = 0; t < kT; t++) {
    const int cur = t & 1, nxt = cur ^ 1;
    const bool lastT = (t == len - 1);
    const uint4* hc = (const uint4*)hH[cur];
    const uint4* tc = (const uint4*)tH[cur];

    float eNext = (s == 0 && t < kT - 1)
                ? out[((uint32_t)(t + 1) * 64u + b) * 512u + h] : 0.f;

    // ---- A1: mhid row h (Wh in VGPRs, Wrs from lane-linear LDS; hid/tops broadcast)
    float acc = 0.f;
    #pragma unroll
    for (int i = 0; i < 8; i++) acc = dot8h(wh[i], hc[(uint32_t)i * 8u + s], acc);
    #pragma unroll
    for (int i = 0; i < 4; i++) {
      acc = dot8h(wrsL[(uint32_t)i * 1024u + r * 8u + s],
                  tc[(uint32_t)i * 8u + s], acc);
    }
    acc += __shfl_xor(acc, 1, 64);
    acc += __shfl_xor(acc, 2, 64);
    acc += __shfl_xor(acc, 4, 64);
    if (s == 0) {
      float v = tanhf(acc + eCur);
      out[((uint32_t)t * 64u + b) * 512u + h] = v;
      if (lastT) out[OUT_HL + b * 512u + h] = v;
      __half vh = __float2half(v);
      uint32_t pay = ((uint32_t)(t + 1) << 16) | (uint32_t)__half_as_ushort(vh);
      __hip_atomic_store(&X32[(((uint32_t)cur * 64u + b) * 4u + q) * 128u + r], pay,
                         __ATOMIC_RELAXED, __HIP_MEMORY_SCOPE_AGENT);
      uint32_t kb = h >> 3, e = h & 7u;
      uint32_t ph = ((kb & 7u) << 3) | (kb >> 3);
      ((__half*)hH[nxt])[ph * 8u + e] = vh;   // own quarter, next buffer
    }
    eCur = eNext;

    // ---- A2: FULL push_vals (replicated; Ws in VGPRs -> no exchange needed)
    float wa2 = 0.f;
    #pragma unroll
    for (int j = 0; j < 8; j++) wa2 = dot8h(wsr[j], hc[((uint32_t)j << 3) | s], wa2);
    wa2 += __shfl_xor(wa2, 1, 64);
    wa2 += __shfl_xor(wa2, 2, 64);
    wa2 += __shfl_xor(wa2, 4, 64);
    if (s == 0) pvL[r] = tanhf(wa2 + bsL[r]);

    // ---- A3: action logits (replicated)
    if (tid < 384u) {
      uint32_t o = tid >> 6, kb = tid & 63u;
      uint32_t ph = ((kb & 7u) << 3) | (kb >> 3);
      float la = dot8h(((const uint4*)waH)[o * 64u + kb], hc[ph], 0.f);
      #pragma unroll
      for (int off = 1; off <= 32; off <<= 1) la += __shfl_xor(la, off, 64);
      if (kb == 0) lgts[o] = la + baL[o];
    }
    __syncthreads();

    // ---- C: stack blend (replicated, bit-identical across the 4 WGs)
    {
      uint32_t c = tid * 4u;
      uint32_t n = c >> 11, sd = (tid >> 4) & 31u, d = c & 63u;
      float l0 = lgts[n * 3u], l1 = lgts[n * 3u + 1u], l2 = lgts[n * 3u + 2u];
      float m = fmaxf(l0, fmaxf(l1, l2));
      float e0 = __expf(l0 - m), e1 = __expf(l1 - m), e2 = __expf(l2 - m);
      float inv = 1.f / (e0 + e1 + e2);
      float p0 = e0 * inv, p1 = e1 * inv, p2 = e2 * inv;
      float4 scur = *(const float4*)&stk[cur][c];
      float4 sp = (sd == 0) ? *(const float4*)&pvL[n * 64u + d]
                            : *(const float4*)&stk[cur][c - 64u];
      float4 so = (sd == 31u) ? *(const float4*)&membL[n * 64u + d]
                              : *(const float4*)&stk[cur][c + 64u];
      float4 nv;
      nv.x = p0 * sp.x + p1 * so.x + p2 * scur.x;
      nv.y = p0 * sp.y + p1 * so.y + p2 * scur.y;
      nv.z = p0 * sp.z + p1 * so.z + p2 * scur.z;
      nv.w = p0 * sp.w + p1 * so.w + p2 * scur.w;
      *(float4*)&stk[nxt][c] = nv;
      if (sd < 2u) {  // new tops -> perm-layout fp16 (next buffer)
        uint32_t f = n * 128u + sd * 64u + d;
        uint32_t jb = f >> 3, e = f & 7u;
        uint32_t pt = ((jb & 3u) << 3) | (jb >> 2);
        uint32_t lo = ((uint32_t)__half_as_ushort(__float2half(nv.y)) << 16) |
                      __half_as_ushort(__float2half(nv.x));
        uint32_t hi = ((uint32_t)__half_as_ushort(__float2half(nv.w)) << 16) |
                      __half_as_ushort(__float2half(nv.z));
        *(uint2*)((__half*)tH[nxt] + pt * 8u + e) = uint2{lo, hi};
      }
      if (lastT && q == 0u) *(float4*)&out[OUT_SR + b * 4096u + c] = nv;
    }

    // ---- gather the 3 foreign hid quarters (store latency hidden under A2/A3/C)
    if (t < kT - 1 && tid < 384u) {
      uint32_t j = tid >> 7;
      uint32_t jj = j + (j >= q ? 1u : 0u);
      uint32_t k = tid & 127u;
      uint32_t* src = &X32[(((uint32_t)cur * 64u + b) * 4u + jj) * 128u + k];
      const uint32_t want = (uint32_t)(t + 1) << 16;
      uint32_t x = __hip_atomic_load(src, __ATOMIC_RELAXED, __HIP_MEMORY_SCOPE_AGENT);
      uint32_t g = 0;
      while ((x & 0xffff0000u) != want) {
        x = __hip_atomic_load(src, __ATOMIC_RELAXED, __HIP_MEMORY_SCOPE_AGENT);
        if (++g > (1u << 24)) break;   // bounded: no hang even if model wrong
      }
      uint32_t idx = jj * 128u + k, kb = idx >> 3, e = idx & 7u;
      uint32_t ph = ((kb & 7u) << 3) | (kb >> 3);
      ((__half*)hH[nxt])[ph * 8u + e] = __ushort_as_half((unsigned short)(x & 0xffffu));
    }
    __syncthreads();
  }
}

extern "C" void kernel_launch(void* const* d_in, const int* in_sizes, int n_in,
                              void* d_out, int out_size, void* d_ws, size_t ws_size,
                              hipStream_t stream) {
  const float* embs = (const float*)d_in[0];
  const int*   lens = (const int*)d_in[1];
  const float* We   = (const float*)d_in[2];
  const float* be   = (const float*)d_in[3];
  const float* Wh   = (const float*)d_in[4];
  const float* bh   = (const float*)d_in[5];
  const float* Wa   = (const float*)d_in[6];
  const float* ba   = (const float*)d_in[7];
  const float* Ws   = (const float*)d_in[8];
  const float* bs   = (const float*)d_in[9];
  const float* Wr   = (const float*)d_in[10];
  const float* br   = (const float*)d_in[11];
  const float* memb = (const float*)d_in[12];
  float* out = (float*)d_out;
  char* ws = (char*)d_ws;

  pack_kernel<<<1024, 256, 0, stream>>>(Wh, Wr, Ws, We, be, bh, br, ws);
  embed_kernel<<<2048, 256, 0, stream>>>(embs, ws, out);
  rnn_kernel<<<256, 1024, 0, stream>>>(lens, Wa, ba, bs, memb, ws, out);
}